// Round 11
// baseline (164.908 us; speedup 1.0000x reference)
//
#include <hip/hip_runtime.h>

// HSI_RWKV fused block kernel, MI355X (gfx950), R19.
// out = block(x) + T(block(T(x))) == 2 * block_per_token(x)  (block is per-token).
// R19 = R17 EXACTLY (NW=16/1024 thr, grid 256, 4 waves/SIMD, whtS-free act
// reuse, wa[4] capture, fp32 residual, split-N gemms, b[4] grouping, LDA=132,
// manual f2bf, no setprio -- ALL R18 changes reverted per m240/T12 "don't
// hand-write cvt_pk": asm pinned operands -> spill +81MB, conflicts +1.4M,
// 66->78 us) + exactly ONE change:
//   t -> Y EARLY WRITE. R17's WRITE_SIZE 45 MB vs 32 ideal = ~13 MB residual
//   scratch: chunk-loop live set (akv32+wa16+a4 16+b16+t32+addr) ~132 >
//   128-reg cap. t1 is finalized in P2 and consumed only at the end, so:
//   write Y = 2*t1 right after LN2 (32 coalesced stores), t[] dead through
//   the chunk loop (-32 regs -> ~92 live, zero spill), final does same-lane
//   same-address Y += 2*prod (RMW; 2*(t1+p) == 2*t1+2*p exactly in fp32).
//   Y stays L2/L3-resident between the two touches; HBM is 13% utilized so
//   the +64 MB round-trip is cheap vs removing the spill.
// MFMA layouts (m89/m91): A m=lane&15,k=q*8+j; B n=lane&15,k=q*8+j;
// D row(token)=q*4+reg, col(out-ch)=lane&15. Frags: short8 bit patterns.

#define HW    16384
#define CDIM  128
#define LDA   132     // act row stride (ushorts); 264 B, 8B-aligned
#define LDW   136     // weight tile row stride (ushorts); 272 B
#define TPW   16      // tokens per wave
#define NW    16      // waves per block (1024 threads)

#define OFF_OUT 0
#define OFF_WHT 16384
#define OFF_KEY 32768
#define OFF_REC 98304
#define OFF_VAL 114688
#define WS_ELEMS 180224   // *2 bytes

typedef __attribute__((ext_vector_type(8))) short short8;  // 8 bf16 bit patterns
typedef __attribute__((ext_vector_type(4))) float f32x4;

__device__ __forceinline__ float bf2f(ushort h) {
    union { uint u; float f; } v; v.u = ((uint)h) << 16; return v.f;
}
__device__ __forceinline__ ushort f2bf(float f) {
    union { float f; uint u; } v; v.f = f;
    uint u = v.u + 0x7fffu + ((v.u >> 16) & 1u);   // RNE
    return (ushort)(u >> 16);
}
__device__ __forceinline__ float sigm(float x) {
    return 1.f / (1.f + __expf(-x));
}

// one-launch weight conversion: 180224 elements, grid 704 x 256 (R7+-proven)
__global__ void cvt_all(const float* __restrict__ Wout, const float* __restrict__ Wwht,
                        const float* __restrict__ Wkey, const float* __restrict__ Wrec,
                        const float* __restrict__ Wval, ushort* __restrict__ ws) {
    int i = blockIdx.x * 256 + threadIdx.x;
    float v;
    if      (i < 32768)  v = (i < 16384) ? Wout[i] : Wwht[i - 16384];
    else if (i < 98304)  v = Wkey[i - 32768];
    else if (i < 114688) v = Wrec[i - 98304];
    else                 v = Wval[i - 114688];
    ws[i] = f2bf(v);
}

// Stage a 128x128 bf16 tile W[row0..row0+128)[k0..k0+128) into Wl (LDW-padded).
// 1024 threads x 16B x 2 iters = 32 KB; batched independent loads.
template<bool PRE>
__device__ __forceinline__ void stageW(ushort* Wl,
                                       const ushort* __restrict__ wsrc,
                                       const float* __restrict__ fsrc,
                                       int src_ld, int row0, int k0, int tid) {
    const int rr = tid >> 4, cc = (tid & 15) * 8;   // rr in 0..63
#pragma unroll
    for (int j = 0; j < 2; ++j) {
        const int r  = j * 64 + rr;
        const int si = (row0 + r) * src_ld + k0 + cc;
        if (PRE) {
            *(short8*)&Wl[r * LDW + cc] = *(const short8*)&wsrc[si];
        } else {
            const float* p = fsrc + si;
            float4 f0 = *(const float4*)p;
            float4 f1 = *(const float4*)(p + 4);
            union { ushort u[8]; short8 s; } t;
            t.u[0]=f2bf(f0.x); t.u[1]=f2bf(f0.y); t.u[2]=f2bf(f0.z); t.u[3]=f2bf(f0.w);
            t.u[4]=f2bf(f1.x); t.u[5]=f2bf(f1.y); t.u[6]=f2bf(f1.z); t.u[7]=f2bf(f1.w);
            *(short8*)&Wl[r * LDW + cc] = t.s;
        }
    }
}

__device__ __forceinline__ short8 ldA8(const ushort* p) {   // 8B-aligned LDS
    union { uint2 x[2]; short8 s; } r;
    r.x[0] = *(const uint2*)p;
    r.x[1] = *(const uint2*)(p + 4);
    return r.s;
}

// acc[nt] += A(16 tok x K=128, wave-local LDS) @ Wl^T; B loaded in groups of 4
// (16-reg transient instead of 32). Same MFMA set/order as R15's gemm16.
__device__ __forceinline__ void gemm16(const ushort* A, const ushort* Wl,
                                       int q, int c, f32x4 acc[8]) {
#pragma unroll
    for (int kk = 0; kk < 4; ++kk) {
        short8 a = ldA8(A + c * LDA + kk * 32 + q * 8);
#pragma unroll
        for (int h = 0; h < 2; ++h) {
            short8 b[4];
#pragma unroll
            for (int g = 0; g < 4; ++g)
                b[g] = *(const short8*)&Wl[((h * 4 + g) * 16 + c) * LDW + kk * 32 + q * 8];
#pragma unroll
            for (int g = 0; g < 4; ++g)
                acc[h * 4 + g] = __builtin_amdgcn_mfma_f32_16x16x32_bf16(
                    a, b[g], acc[h * 4 + g], 0, 0, 0);
        }
    }
}

// half-N gemm from registers (wa[]): acc4[g] covers nt = nt0+g, g in [0,4).
// 16-reg accumulator + 16-reg B transient; acc4 dead between halves.
__device__ __forceinline__ void gemm8r(const short8* wa, const ushort* Wl,
                                       int nt0, int q, int c, f32x4 acc4[4]) {
#pragma unroll
    for (int kk = 0; kk < 4; ++kk) {
        short8 b[4];
#pragma unroll
        for (int g = 0; g < 4; ++g)
            b[g] = *(const short8*)&Wl[((nt0 + g) * 16 + c) * LDW + kk * 32 + q * 8];
#pragma unroll
        for (int g = 0; g < 4; ++g)
            acc4[g] = __builtin_amdgcn_mfma_f32_16x16x32_bf16(
                wa[kk], b[g], acc4[g], 0, 0, 0);
    }
}

__device__ __forceinline__ void zero8(f32x4 a[8]) {
#pragma unroll
    for (int nt = 0; nt < 8; ++nt) a[nt] = (f32x4){0.f, 0.f, 0.f, 0.f};
}
__device__ __forceinline__ void zero4(f32x4 a[4]) {
#pragma unroll
    for (int g = 0; g < 4; ++g) a[g] = (f32x4){0.f, 0.f, 0.f, 0.f};
}

// per-token LN stats (R5-proven): token = lane&15, partials across 4 quads
__device__ __forceinline__ void ln_stats(const float* t, float& mu, float& rs) {
    float s1 = 0.f, s2 = 0.f;
#pragma unroll
    for (int i = 0; i < 32; ++i) { s1 += t[i]; s2 += t[i] * t[i]; }
    s1 += __shfl_xor(s1, 16); s2 += __shfl_xor(s2, 16);
    s1 += __shfl_xor(s1, 32); s2 += __shfl_xor(s2, 32);
    mu = s1 * (1.f / 128.f);
    rs = rsqrtf(s2 * (1.f / 128.f) - mu * mu + 1e-5f);
}

template<bool PRE>
__global__ __launch_bounds__(1024, 4) void rwkv_mfma(
    const float* __restrict__ X,
    const float* __restrict__ G0, const float* __restrict__ B0,
    const float* __restrict__ G1, const float* __restrict__ B1,
    const float* __restrict__ G2, const float* __restrict__ B2,
    const float* __restrict__ WoutF, const float* __restrict__ WwhtF,
    const float* __restrict__ WkeyF, const float* __restrict__ WrecF,
    const float* __restrict__ WvalF,
    const ushort* __restrict__ Wb,
    float* __restrict__ Y)
{
    __shared__ __align__(16) ushort actS[NW * TPW * LDA];   // 67584 B wave-local
    __shared__ __align__(16) ushort WldsA[128 * LDW];       // 34816 B: OUT,KEY*,REC
    __shared__ __align__(16) ushort WldsB[128 * LDW];       // 34816 B: WHT,VAL*
    // total 137216 B -> 1 block/CU; 16 waves/CU = 4 waves/SIMD

    const int tid = threadIdx.x;
    const int w = tid >> 6, l = tid & 63;
    const int q = l >> 4, c = l & 15;
    ushort* act = actS + w * (TPW * LDA);   // a1 / att / y2 / wht / k-chunk / prod

    const int s256 = blockIdx.x * 256;         // 256 tokens per block (16 waves x 16)
    const int bb  = s256 >> 14;
    const int s0  = s256 & (HW - 1);           // 16384%256==0: blocks never cross batch
    const long gbase = (long)(bb * CDIM) * HW + s0 + 16 * w + c;

    // ==== P0: stage OUT -> A (overlaps X loads + LN0/LN1) ====
    stageW<PRE>(WldsA, Wb + OFF_OUT, WoutF, 128, 0, 0, tid);

    float t[32];                               // fp32 residual (numerically required)
#pragma unroll
    for (int i = 0; i < 32; ++i) t[i] = X[gbase + (long)(32 * q + i) * HW];

    float mu, rs;
    ln_stats(t, mu, rs);                       // LN0
#pragma unroll
    for (int i = 0; i < 32; ++i) {
        int ch = 32 * q + i;
        t[i] = (t[i] - mu) * rs * G0[ch] + B0[ch];
    }
    ln_stats(t, mu, rs);                       // LN1 + silu -> act (a1)
#pragma unroll
    for (int j = 0; j < 16; ++j) {
        int ch = 32 * q + 2 * j;
        float y0 = (t[2*j]   - mu) * rs * G1[ch]   + B1[ch];
        float y1 = (t[2*j+1] - mu) * rs * G1[ch+1] + B1[ch+1];
        y0 *= sigm(y0); y1 *= sigm(y1);
        *(uint*)&act[c * LDA + ch] = (uint)f2bf(y0) | ((uint)f2bf(y1) << 16);
    }
    __syncthreads();                           // OUT staged

    // ==== P1: att = a1 @ W_out^T (A); stage WHT -> B; t1 = t + att ====
    stageW<PRE>(WldsB, Wb + OFF_WHT, WwhtF, 128, 0, 0, tid);
    {
        f32x4 acc[8];
        zero8(acc);
        gemm16(act, WldsA, q, c, acc);
        // D-store att -> act (overwrites a1; gemm reads precede in-wave)
#pragma unroll
        for (int nt = 0; nt < 8; ++nt)
#pragma unroll
            for (int r = 0; r < 4; ++r)
                act[(q * 4 + r) * LDA + nt * 16 + c] = f2bf(acc[nt][r]);
    }
    // in-wave cross-lane write->read (R8/R14/R15/R17-proven pattern class)
#pragma unroll
    for (int i = 0; i < 32; ++i)
        t[i] += bf2f(act[c * LDA + 32 * q + i]);    // t1 = t + att
    __syncthreads();                           // WHT staged, A free

    // ==== P2: y2 = LN2(t1) -> act; Y = 2*t1 (t dead after); wht = y2 @
    //          W_whiten^T (B) -> act; wa[] capture; stage KEY0 -> A ====
    stageW<PRE>(WldsA, Wb + OFF_KEY, WkeyF, 128, 0, 0, tid);
    ln_stats(t, mu, rs);                       // LN2
#pragma unroll
    for (int j = 0; j < 16; ++j) {
        int ch = 32 * q + 2 * j;
        float y0 = (t[2*j]   - mu) * rs * G2[ch]   + B2[ch];
        float y1 = (t[2*j+1] - mu) * rs * G2[ch+1] + B2[ch+1];
        *(uint*)&act[c * LDA + ch] = (uint)f2bf(y0) | ((uint)f2bf(y1) << 16);
    }
    // EARLY residual write: Y = 2*t1. Frees t[] (32 VGPR) for the chunk loop.
    // Final phase does same-lane same-address Y += 2*prod (exact: 2*(a+b)==2a+2b).
#pragma unroll
    for (int i = 0; i < 32; ++i)
        Y[gbase + (long)(32 * q + i) * HW] = 2.f * t[i];
    {
        f32x4 acc[8];
        zero8(acc);
        gemm16(act, WldsB, q, c, acc);         // y2 writes precede reads in-wave
#pragma unroll
        for (int nt = 0; nt < 8; ++nt)         // D-store wht -> act
#pragma unroll
            for (int r = 0; r < 4; ++r)
                act[(q * 4 + r) * LDA + nt * 16 + c] = f2bf(acc[nt][r]);
    }
    // capture A-frags (same bf16 bits KEY/REC gemms would re-read); in-wave
    // cross-lane write->read, proven in R14/R15/R17.
    short8 wa[4];
#pragma unroll
    for (int kk = 0; kk < 4; ++kk)
        wa[kk] = ldA8(act + c * LDA + kk * 32 + q * 8);
    __syncthreads();                           // KEY0 staged, B free

    // ==== chunks: KEY_c on A (stage VAL_c -> B); VAL_c on B (stage next -> A) ====
    f32x4 akv[8];
    zero8(akv);
    for (int chunk = 0; chunk < 4; ++chunk) {
        // KEY phase: k = relu(wa @ W_key_c^T)^2 -> act, two half-N passes
        stageW<PRE>(WldsB, Wb + OFF_VAL, WvalF, 512, 0, chunk * 128, tid);
#pragma unroll
        for (int h = 0; h < 2; ++h) {
            f32x4 a4[4];
            zero4(a4);
            gemm8r(wa, WldsA, h * 4, q, c, a4);
#pragma unroll
            for (int g = 0; g < 4; ++g)
#pragma unroll
                for (int r = 0; r < 4; ++r) {
                    float v = fmaxf(a4[g][r], 0.f);
                    act[(q * 4 + r) * LDA + (h * 4 + g) * 16 + c] = f2bf(v * v);
                }
        }
        __syncthreads();                       // VAL_c staged, A free

        // VAL phase: akv += k @ W_value_c^T (k read from act, same wave wrote it)
        if (chunk < 3)
            stageW<PRE>(WldsA, Wb + OFF_KEY, WkeyF, 128, (chunk + 1) * 128, 0, tid);
        else
            stageW<PRE>(WldsA, Wb + OFF_REC, WrecF, 128, 0, 0, tid);
        gemm16(act, WldsB, q, c, akv);
        __syncthreads();                       // next tile staged, B free
    }

    // ==== P11: r = sigmoid(wa @ W_recep^T) (A); prod = r*kv -> act,
    //           two half-N passes ====
#pragma unroll
    for (int h = 0; h < 2; ++h) {
        f32x4 a4[4];
        zero4(a4);
        gemm8r(wa, WldsA, h * 4, q, c, a4);
#pragma unroll
        for (int g = 0; g < 4; ++g)
#pragma unroll
            for (int r = 0; r < 4; ++r)
                act[(q * 4 + r) * LDA + (h * 4 + g) * 16 + c] =
                    f2bf(sigm(a4[g][r]) * akv[h * 4 + g][r]);
    }
    // no barrier: act is wave-local; in-wave DS ordering covers the reads below.

    // ==== out: Y += 2*prod (same lane + address as the early write) ====
#pragma unroll
    for (int i = 0; i < 32; ++i) {
        const long yi = gbase + (long)(32 * q + i) * HW;
        Y[yi] = Y[yi] + 2.f * bf2f(act[c * LDA + 32 * q + i]);
    }
}

extern "C" void kernel_launch(void* const* d_in, const int* in_sizes, int n_in,
                              void* d_out, int out_size, void* d_ws, size_t ws_size,
                              hipStream_t stream) {
    (void)in_sizes; (void)n_in; (void)out_size;
    const float* X  = (const float*)d_in[0];
    const float* G0 = (const float*)d_in[1];  const float* B0 = (const float*)d_in[2];
    const float* G1 = (const float*)d_in[3];  const float* B1 = (const float*)d_in[4];
    const float* G2 = (const float*)d_in[5];  const float* B2 = (const float*)d_in[6];
    const float* Wout = (const float*)d_in[7];
    const float* Wwht = (const float*)d_in[8];
    const float* Wkey = (const float*)d_in[9];
    const float* Wrec = (const float*)d_in[10];
    const float* Wval = (const float*)d_in[11];
    float* Y = (float*)d_out;

    const bool pre = ws_size >= (size_t)WS_ELEMS * 2;
    if (pre) {
        ushort* ws = (ushort*)d_ws;
        cvt_all<<<704, 256, 0, stream>>>(Wout, Wwht, Wkey, Wrec, Wval, ws);
        rwkv_mfma<true><<<256, 1024, 0, stream>>>(
            X, G0, B0, G1, B1, G2, B2,
            Wout, Wwht, Wkey, Wrec, Wval, ws, Y);
    } else {
        rwkv_mfma<false><<<256, 1024, 0, stream>>>(
            X, G0, B0, G1, B1, G2, B2,
            Wout, Wwht, Wkey, Wrec, Wval, nullptr, Y);
    }
}

// Round 12
// 156.584 us; speedup vs baseline: 1.0532x; 1.0532x over previous
//
#include <hip/hip_runtime.h>
#include <hip/hip_bf16.h>

// HSI_RWKV fused block kernel, MI355X (gfx950), R20.
// out = block(x) + T(block(T(x))) == 2 * block_per_token(x)  (block is per-token).
// R20 = R17 EXACTLY (NW=16/1024 thr, grid 256, 4 waves/SIMD, whtS-free act
// reuse, wa[4] capture, fp32 residual t (kept to the END -- R19's early-write
// Y round-trip REVERTED: L2 evictions made traffic 71->165 MB, 66->82 us),
// split-N gemms, b[4] grouping, LDA=132, no setprio) + exactly ONE change:
//   NATIVE bf16 CONVERSION: manual 4-op RNE f2bf -> __float2bfloat16 (the
//   m240/T12-sanctioned scalar-cast form). Compiler lowers to HW
//   v_cvt_pk_bf16_f32 but stays free to schedule/rematerialize -- avoiding
//   R18's inline-asm operand pinning (which re-spilled: +81 MB, 66->78 us)
//   while keeping its real VALU cut (R18 showed VALUBusy 34->24.5).
//   ~900 conversion ops/wave -> ~250. Worst case (header fallback) the ops
//   are identical to R17 -> upside-only.
// MFMA layouts (m89/m91): A m=lane&15,k=q*8+j; B n=lane&15,k=q*8+j;
// D row(token)=q*4+reg, col(out-ch)=lane&15. Frags: short8 bit patterns.

#define HW    16384
#define CDIM  128
#define LDA   132     // act row stride (ushorts); 264 B, 8B-aligned
#define LDW   136     // weight tile row stride (ushorts); 272 B
#define TPW   16      // tokens per wave
#define NW    16      // waves per block (1024 threads)

#define OFF_OUT 0
#define OFF_WHT 16384
#define OFF_KEY 32768
#define OFF_REC 98304
#define OFF_VAL 114688
#define WS_ELEMS 180224   // *2 bytes

typedef __attribute__((ext_vector_type(8))) short short8;  // 8 bf16 bit patterns
typedef __attribute__((ext_vector_type(4))) float f32x4;

__device__ __forceinline__ float bf2f(ushort h) {
    union { uint u; float f; } v; v.u = ((uint)h) << 16; return v.f;
}
// native bf16 conversion (RNE): compiler emits v_cvt_pk_bf16_f32, schedulable
__device__ __forceinline__ ushort f2bf(float f) {
    union { __hip_bfloat16 h; ushort u; } v;
    v.h = __float2bfloat16(f);
    return v.u;
}
__device__ __forceinline__ uint pk2(float a, float b) {
    return (uint)f2bf(a) | ((uint)f2bf(b) << 16);
}
__device__ __forceinline__ float sigm(float x) {
    return 1.f / (1.f + __expf(-x));
}

// one-launch weight conversion: 180224 elements, grid 704 x 256 (R7+-proven)
__global__ void cvt_all(const float* __restrict__ Wout, const float* __restrict__ Wwht,
                        const float* __restrict__ Wkey, const float* __restrict__ Wrec,
                        const float* __restrict__ Wval, ushort* __restrict__ ws) {
    int i = blockIdx.x * 256 + threadIdx.x;
    float v;
    if      (i < 32768)  v = (i < 16384) ? Wout[i] : Wwht[i - 16384];
    else if (i < 98304)  v = Wkey[i - 32768];
    else if (i < 114688) v = Wrec[i - 98304];
    else                 v = Wval[i - 114688];
    ws[i] = f2bf(v);
}

// Stage a 128x128 bf16 tile W[row0..row0+128)[k0..k0+128) into Wl (LDW-padded).
// 1024 threads x 16B x 2 iters = 32 KB; batched independent loads.
template<bool PRE>
__device__ __forceinline__ void stageW(ushort* Wl,
                                       const ushort* __restrict__ wsrc,
                                       const float* __restrict__ fsrc,
                                       int src_ld, int row0, int k0, int tid) {
    const int rr = tid >> 4, cc = (tid & 15) * 8;   // rr in 0..63
#pragma unroll
    for (int j = 0; j < 2; ++j) {
        const int r  = j * 64 + rr;
        const int si = (row0 + r) * src_ld + k0 + cc;
        if (PRE) {
            *(short8*)&Wl[r * LDW + cc] = *(const short8*)&wsrc[si];
        } else {
            const float* p = fsrc + si;
            float4 f0 = *(const float4*)p;
            float4 f1 = *(const float4*)(p + 4);
            union { uint u[4]; short8 s; } t;
            t.u[0] = pk2(f0.x, f0.y); t.u[1] = pk2(f0.z, f0.w);
            t.u[2] = pk2(f1.x, f1.y); t.u[3] = pk2(f1.z, f1.w);
            *(short8*)&Wl[r * LDW + cc] = t.s;
        }
    }
}

__device__ __forceinline__ short8 ldA8(const ushort* p) {   // 8B-aligned LDS
    union { uint2 x[2]; short8 s; } r;
    r.x[0] = *(const uint2*)p;
    r.x[1] = *(const uint2*)(p + 4);
    return r.s;
}

// acc[nt] += A(16 tok x K=128, wave-local LDS) @ Wl^T; B loaded in groups of 4
// (16-reg transient instead of 32). Same MFMA set/order as R15's gemm16.
__device__ __forceinline__ void gemm16(const ushort* A, const ushort* Wl,
                                       int q, int c, f32x4 acc[8]) {
#pragma unroll
    for (int kk = 0; kk < 4; ++kk) {
        short8 a = ldA8(A + c * LDA + kk * 32 + q * 8);
#pragma unroll
        for (int h = 0; h < 2; ++h) {
            short8 b[4];
#pragma unroll
            for (int g = 0; g < 4; ++g)
                b[g] = *(const short8*)&Wl[((h * 4 + g) * 16 + c) * LDW + kk * 32 + q * 8];
#pragma unroll
            for (int g = 0; g < 4; ++g)
                acc[h * 4 + g] = __builtin_amdgcn_mfma_f32_16x16x32_bf16(
                    a, b[g], acc[h * 4 + g], 0, 0, 0);
        }
    }
}

// half-N gemm from registers (wa[]): acc4[g] covers nt = nt0+g, g in [0,4).
// 16-reg accumulator + 16-reg B transient; acc4 dead between halves.
__device__ __forceinline__ void gemm8r(const short8* wa, const ushort* Wl,
                                       int nt0, int q, int c, f32x4 acc4[4]) {
#pragma unroll
    for (int kk = 0; kk < 4; ++kk) {
        short8 b[4];
#pragma unroll
        for (int g = 0; g < 4; ++g)
            b[g] = *(const short8*)&Wl[((nt0 + g) * 16 + c) * LDW + kk * 32 + q * 8];
#pragma unroll
        for (int g = 0; g < 4; ++g)
            acc4[g] = __builtin_amdgcn_mfma_f32_16x16x32_bf16(
                wa[kk], b[g], acc4[g], 0, 0, 0);
    }
}

__device__ __forceinline__ void zero8(f32x4 a[8]) {
#pragma unroll
    for (int nt = 0; nt < 8; ++nt) a[nt] = (f32x4){0.f, 0.f, 0.f, 0.f};
}
__device__ __forceinline__ void zero4(f32x4 a[4]) {
#pragma unroll
    for (int g = 0; g < 4; ++g) a[g] = (f32x4){0.f, 0.f, 0.f, 0.f};
}

// per-token LN stats (R5-proven): token = lane&15, partials across 4 quads
__device__ __forceinline__ void ln_stats(const float* t, float& mu, float& rs) {
    float s1 = 0.f, s2 = 0.f;
#pragma unroll
    for (int i = 0; i < 32; ++i) { s1 += t[i]; s2 += t[i] * t[i]; }
    s1 += __shfl_xor(s1, 16); s2 += __shfl_xor(s2, 16);
    s1 += __shfl_xor(s1, 32); s2 += __shfl_xor(s2, 32);
    mu = s1 * (1.f / 128.f);
    rs = rsqrtf(s2 * (1.f / 128.f) - mu * mu + 1e-5f);
}

template<bool PRE>
__global__ __launch_bounds__(1024, 4) void rwkv_mfma(
    const float* __restrict__ X,
    const float* __restrict__ G0, const float* __restrict__ B0,
    const float* __restrict__ G1, const float* __restrict__ B1,
    const float* __restrict__ G2, const float* __restrict__ B2,
    const float* __restrict__ WoutF, const float* __restrict__ WwhtF,
    const float* __restrict__ WkeyF, const float* __restrict__ WrecF,
    const float* __restrict__ WvalF,
    const ushort* __restrict__ Wb,
    float* __restrict__ Y)
{
    __shared__ __align__(16) ushort actS[NW * TPW * LDA];   // 67584 B wave-local
    __shared__ __align__(16) ushort WldsA[128 * LDW];       // 34816 B: OUT,KEY*,REC
    __shared__ __align__(16) ushort WldsB[128 * LDW];       // 34816 B: WHT,VAL*
    // total 137216 B -> 1 block/CU; 16 waves/CU = 4 waves/SIMD

    const int tid = threadIdx.x;
    const int w = tid >> 6, l = tid & 63;
    const int q = l >> 4, c = l & 15;
    ushort* act = actS + w * (TPW * LDA);   // a1 / att / y2 / wht / k-chunk / prod

    const int s256 = blockIdx.x * 256;         // 256 tokens per block (16 waves x 16)
    const int bb  = s256 >> 14;
    const int s0  = s256 & (HW - 1);           // 16384%256==0: blocks never cross batch
    const long gbase = (long)(bb * CDIM) * HW + s0 + 16 * w + c;

    // ==== P0: stage OUT -> A (overlaps X loads + LN0/LN1) ====
    stageW<PRE>(WldsA, Wb + OFF_OUT, WoutF, 128, 0, 0, tid);

    float t[32];                               // fp32 residual (numerically required)
#pragma unroll
    for (int i = 0; i < 32; ++i) t[i] = X[gbase + (long)(32 * q + i) * HW];

    float mu, rs;
    ln_stats(t, mu, rs);                       // LN0
#pragma unroll
    for (int i = 0; i < 32; ++i) {
        int ch = 32 * q + i;
        t[i] = (t[i] - mu) * rs * G0[ch] + B0[ch];
    }
    ln_stats(t, mu, rs);                       // LN1 + silu -> act (a1)
#pragma unroll
    for (int j = 0; j < 16; ++j) {
        int ch = 32 * q + 2 * j;
        float y0 = (t[2*j]   - mu) * rs * G1[ch]   + B1[ch];
        float y1 = (t[2*j+1] - mu) * rs * G1[ch+1] + B1[ch+1];
        y0 *= sigm(y0); y1 *= sigm(y1);
        *(uint*)&act[c * LDA + ch] = pk2(y0, y1);
    }
    __syncthreads();                           // OUT staged

    // ==== P1: att = a1 @ W_out^T (A); stage WHT -> B; t1 = t + att ====
    stageW<PRE>(WldsB, Wb + OFF_WHT, WwhtF, 128, 0, 0, tid);
    {
        f32x4 acc[8];
        zero8(acc);
        gemm16(act, WldsA, q, c, acc);
        // D-store att -> act (overwrites a1; gemm reads precede in-wave)
#pragma unroll
        for (int nt = 0; nt < 8; ++nt)
#pragma unroll
            for (int r = 0; r < 4; ++r)
                act[(q * 4 + r) * LDA + nt * 16 + c] = f2bf(acc[nt][r]);
    }
    // in-wave cross-lane write->read (R8/R14/R15/R17-proven pattern class)
#pragma unroll
    for (int i = 0; i < 32; ++i)
        t[i] += bf2f(act[c * LDA + 32 * q + i]);    // t1 = t + att
    __syncthreads();                           // WHT staged, A free

    // ==== P2: y2 = LN2(t1) -> act; wht = y2 @ W_whiten^T (B) -> act;
    //          wa[] capture; stage KEY0 -> A ====
    stageW<PRE>(WldsA, Wb + OFF_KEY, WkeyF, 128, 0, 0, tid);
    ln_stats(t, mu, rs);                       // LN2
#pragma unroll
    for (int j = 0; j < 16; ++j) {
        int ch = 32 * q + 2 * j;
        float y0 = (t[2*j]   - mu) * rs * G2[ch]   + B2[ch];
        float y1 = (t[2*j+1] - mu) * rs * G2[ch+1] + B2[ch+1];
        *(uint*)&act[c * LDA + ch] = pk2(y0, y1);
    }
    {
        f32x4 acc[8];
        zero8(acc);
        gemm16(act, WldsB, q, c, acc);         // y2 writes precede reads in-wave
#pragma unroll
        for (int nt = 0; nt < 8; ++nt)         // D-store wht -> act
#pragma unroll
            for (int r = 0; r < 4; ++r)
                act[(q * 4 + r) * LDA + nt * 16 + c] = f2bf(acc[nt][r]);
    }
    // capture A-frags (same bf16 bits KEY/REC gemms would re-read); in-wave
    // cross-lane write->read, proven in R14/R15/R17.
    short8 wa[4];
#pragma unroll
    for (int kk = 0; kk < 4; ++kk)
        wa[kk] = ldA8(act + c * LDA + kk * 32 + q * 8);
    __syncthreads();                           // KEY0 staged, B free

    // ==== chunks: KEY_c on A (stage VAL_c -> B); VAL_c on B (stage next -> A) ====
    f32x4 akv[8];
    zero8(akv);
    for (int chunk = 0; chunk < 4; ++chunk) {
        // KEY phase: k = relu(wa @ W_key_c^T)^2 -> act, two half-N passes
        stageW<PRE>(WldsB, Wb + OFF_VAL, WvalF, 512, 0, chunk * 128, tid);
#pragma unroll
        for (int h = 0; h < 2; ++h) {
            f32x4 a4[4];
            zero4(a4);
            gemm8r(wa, WldsA, h * 4, q, c, a4);
#pragma unroll
            for (int g = 0; g < 4; ++g)
#pragma unroll
                for (int r = 0; r < 4; ++r) {
                    float v = fmaxf(a4[g][r], 0.f);
                    act[(q * 4 + r) * LDA + (h * 4 + g) * 16 + c] = f2bf(v * v);
                }
        }
        __syncthreads();                       // VAL_c staged, A free

        // VAL phase: akv += k @ W_value_c^T (k read from act, same wave wrote it)
        if (chunk < 3)
            stageW<PRE>(WldsA, Wb + OFF_KEY, WkeyF, 128, (chunk + 1) * 128, 0, tid);
        else
            stageW<PRE>(WldsA, Wb + OFF_REC, WrecF, 128, 0, 0, tid);
        gemm16(act, WldsB, q, c, akv);
        __syncthreads();                       // next tile staged, B free
    }

    // ==== P11: r = sigmoid(wa @ W_recep^T) (A); prod = r*kv -> act,
    //           two half-N passes ====
#pragma unroll
    for (int h = 0; h < 2; ++h) {
        f32x4 a4[4];
        zero4(a4);
        gemm8r(wa, WldsA, h * 4, q, c, a4);
#pragma unroll
        for (int g = 0; g < 4; ++g)
#pragma unroll
            for (int r = 0; r < 4; ++r)
                act[(q * 4 + r) * LDA + (h * 4 + g) * 16 + c] =
                    f2bf(sigm(a4[g][r]) * akv[h * 4 + g][r]);
    }
    // no barrier: act is wave-local; in-wave DS ordering covers the reads below.

    // ==== out = 2 * (t1 + r*kv) ====
#pragma unroll
    for (int i = 0; i < 32; ++i) {
        float t2 = t[i] + bf2f(act[c * LDA + 32 * q + i]);
        Y[gbase + (long)(32 * q + i) * HW] = 2.f * t2;
    }
}

extern "C" void kernel_launch(void* const* d_in, const int* in_sizes, int n_in,
                              void* d_out, int out_size, void* d_ws, size_t ws_size,
                              hipStream_t stream) {
    (void)in_sizes; (void)n_in; (void)out_size;
    const float* X  = (const float*)d_in[0];
    const float* G0 = (const float*)d_in[1];  const float* B0 = (const float*)d_in[2];
    const float* G1 = (const float*)d_in[3];  const float* B1 = (const float*)d_in[4];
    const float* G2 = (const float*)d_in[5];  const float* B2 = (const float*)d_in[6];
    const float* Wout = (const float*)d_in[7];
    const float* Wwht = (const float*)d_in[8];
    const float* Wkey = (const float*)d_in[9];
    const float* Wrec = (const float*)d_in[10];
    const float* Wval = (const float*)d_in[11];
    float* Y = (float*)d_out;

    const bool pre = ws_size >= (size_t)WS_ELEMS * 2;
    if (pre) {
        ushort* ws = (ushort*)d_ws;
        cvt_all<<<704, 256, 0, stream>>>(Wout, Wwht, Wkey, Wrec, Wval, ws);
        rwkv_mfma<true><<<256, 1024, 0, stream>>>(
            X, G0, B0, G1, B1, G2, B2,
            Wout, Wwht, Wkey, Wrec, Wval, ws, Y);
    } else {
        rwkv_mfma<false><<<256, 1024, 0, stream>>>(
            X, G0, B0, G1, B1, G2, B2,
            Wout, Wwht, Wkey, Wrec, Wval, nullptr, Y);
    }
}

// Round 13
// 153.148 us; speedup vs baseline: 1.0768x; 1.0224x over previous
//
#include <hip/hip_runtime.h>
#include <hip/hip_bf16.h>

// HSI_RWKV fused block kernel, MI355X (gfx950), R21.
// out = block(x) + T(block(T(x))) == 2 * block_per_token(x)  (block is per-token).
// R21 = R20 EXACTLY (NW=16/1024 thr, grid 256, 4 waves/SIMD, whtS-free act
// reuse, wa[4] capture, fp32 residual t, split-N gemms, LDA=132, native
// __float2bfloat16) + exactly ONE change:
//   B-TRANSIENT b[4] -> b[2] IN ALL GEMMS. R17/R20 counters show a
//   persistent ~16-20 MB scratch round-trip (WRITE 49.7 vs 33.5 ideal):
//   chunk-loop arch-side live set t32+wa16+b16+addr~8 = 72 > 64 arch slots
//   (AGPR half holds akv+a4 under the 128-unified cap forced by 4 waves/
//   SIMD). Halving the B transient to pairs (8 regs) brings live to ~64.
//   Bit-identical math: same MFMA set, same per-acc kk-order; only load
//   grouping granularity changes. ILP 4->2 per cluster is covered by TLP
//   at 4 waves/SIMD (same tradeoff R17's split-N already made, +0 cost).
// History: R18 cvt_pk-asm REVERTED (operand pinning respilled, m240/T12);
// R19 Y-early-write REVERTED (L2 evictions, +94 MB). R16 bf16-t REVERTED
// (LN2 numerics). Champion lineage: R13(74) -> R17(66) -> R20(67/156.6).
// MFMA layouts (m89/m91): A m=lane&15,k=q*8+j; B n=lane&15,k=q*8+j;
// D row(token)=q*4+reg, col(out-ch)=lane&15. Frags: short8 bit patterns.

#define HW    16384
#define CDIM  128
#define LDA   132     // act row stride (ushorts); 264 B, 8B-aligned
#define LDW   136     // weight tile row stride (ushorts); 272 B
#define TPW   16      // tokens per wave
#define NW    16      // waves per block (1024 threads)

#define OFF_OUT 0
#define OFF_WHT 16384
#define OFF_KEY 32768
#define OFF_REC 98304
#define OFF_VAL 114688
#define WS_ELEMS 180224   // *2 bytes

typedef __attribute__((ext_vector_type(8))) short short8;  // 8 bf16 bit patterns
typedef __attribute__((ext_vector_type(4))) float f32x4;

__device__ __forceinline__ float bf2f(ushort h) {
    union { uint u; float f; } v; v.u = ((uint)h) << 16; return v.f;
}
// native bf16 conversion (RNE): compiler-lowered, schedulable (m240-sanctioned)
__device__ __forceinline__ ushort f2bf(float f) {
    union { __hip_bfloat16 h; ushort u; } v;
    v.h = __float2bfloat16(f);
    return v.u;
}
__device__ __forceinline__ uint pk2(float a, float b) {
    return (uint)f2bf(a) | ((uint)f2bf(b) << 16);
}
__device__ __forceinline__ float sigm(float x) {
    return 1.f / (1.f + __expf(-x));
}

// one-launch weight conversion: 180224 elements, grid 704 x 256 (R7+-proven)
__global__ void cvt_all(const float* __restrict__ Wout, const float* __restrict__ Wwht,
                        const float* __restrict__ Wkey, const float* __restrict__ Wrec,
                        const float* __restrict__ Wval, ushort* __restrict__ ws) {
    int i = blockIdx.x * 256 + threadIdx.x;
    float v;
    if      (i < 32768)  v = (i < 16384) ? Wout[i] : Wwht[i - 16384];
    else if (i < 98304)  v = Wkey[i - 32768];
    else if (i < 114688) v = Wrec[i - 98304];
    else                 v = Wval[i - 114688];
    ws[i] = f2bf(v);
}

// Stage a 128x128 bf16 tile W[row0..row0+128)[k0..k0+128) into Wl (LDW-padded).
// 1024 threads x 16B x 2 iters = 32 KB; batched independent loads.
template<bool PRE>
__device__ __forceinline__ void stageW(ushort* Wl,
                                       const ushort* __restrict__ wsrc,
                                       const float* __restrict__ fsrc,
                                       int src_ld, int row0, int k0, int tid) {
    const int rr = tid >> 4, cc = (tid & 15) * 8;   // rr in 0..63
#pragma unroll
    for (int j = 0; j < 2; ++j) {
        const int r  = j * 64 + rr;
        const int si = (row0 + r) * src_ld + k0 + cc;
        if (PRE) {
            *(short8*)&Wl[r * LDW + cc] = *(const short8*)&wsrc[si];
        } else {
            const float* p = fsrc + si;
            float4 f0 = *(const float4*)p;
            float4 f1 = *(const float4*)(p + 4);
            union { uint u[4]; short8 s; } t;
            t.u[0] = pk2(f0.x, f0.y); t.u[1] = pk2(f0.z, f0.w);
            t.u[2] = pk2(f1.x, f1.y); t.u[3] = pk2(f1.z, f1.w);
            *(short8*)&Wl[r * LDW + cc] = t.s;
        }
    }
}

__device__ __forceinline__ short8 ldA8(const ushort* p) {   // 8B-aligned LDS
    union { uint2 x[2]; short8 s; } r;
    r.x[0] = *(const uint2*)p;
    r.x[1] = *(const uint2*)(p + 4);
    return r.s;
}

// acc[nt] += A(16 tok x K=128, wave-local LDS) @ Wl^T; B loaded in PAIRS
// (8-reg transient). Same MFMA set and per-acc kk-order as R17/R20.
__device__ __forceinline__ void gemm16(const ushort* A, const ushort* Wl,
                                       int q, int c, f32x4 acc[8]) {
#pragma unroll
    for (int kk = 0; kk < 4; ++kk) {
        short8 a = ldA8(A + c * LDA + kk * 32 + q * 8);
#pragma unroll
        for (int h = 0; h < 4; ++h) {
            short8 b[2];
#pragma unroll
            for (int g = 0; g < 2; ++g)
                b[g] = *(const short8*)&Wl[((h * 2 + g) * 16 + c) * LDW + kk * 32 + q * 8];
#pragma unroll
            for (int g = 0; g < 2; ++g)
                acc[h * 2 + g] = __builtin_amdgcn_mfma_f32_16x16x32_bf16(
                    a, b[g], acc[h * 2 + g], 0, 0, 0);
        }
    }
}

// half-N gemm from registers (wa[]): acc4[g] covers nt = nt0+g, g in [0,4).
// B in pairs (8-reg transient); acc4 dead between halves.
__device__ __forceinline__ void gemm8r(const short8* wa, const ushort* Wl,
                                       int nt0, int q, int c, f32x4 acc4[4]) {
#pragma unroll
    for (int kk = 0; kk < 4; ++kk) {
#pragma unroll
        for (int h = 0; h < 2; ++h) {
            short8 b[2];
#pragma unroll
            for (int g = 0; g < 2; ++g)
                b[g] = *(const short8*)&Wl[((nt0 + h * 2 + g) * 16 + c) * LDW + kk * 32 + q * 8];
#pragma unroll
            for (int g = 0; g < 2; ++g)
                acc4[h * 2 + g] = __builtin_amdgcn_mfma_f32_16x16x32_bf16(
                    wa[kk], b[g], acc4[h * 2 + g], 0, 0, 0);
        }
    }
}

__device__ __forceinline__ void zero8(f32x4 a[8]) {
#pragma unroll
    for (int nt = 0; nt < 8; ++nt) a[nt] = (f32x4){0.f, 0.f, 0.f, 0.f};
}
__device__ __forceinline__ void zero4(f32x4 a[4]) {
#pragma unroll
    for (int g = 0; g < 4; ++g) a[g] = (f32x4){0.f, 0.f, 0.f, 0.f};
}

// per-token LN stats (R5-proven): token = lane&15, partials across 4 quads
__device__ __forceinline__ void ln_stats(const float* t, float& mu, float& rs) {
    float s1 = 0.f, s2 = 0.f;
#pragma unroll
    for (int i = 0; i < 32; ++i) { s1 += t[i]; s2 += t[i] * t[i]; }
    s1 += __shfl_xor(s1, 16); s2 += __shfl_xor(s2, 16);
    s1 += __shfl_xor(s1, 32); s2 += __shfl_xor(s2, 32);
    mu = s1 * (1.f / 128.f);
    rs = rsqrtf(s2 * (1.f / 128.f) - mu * mu + 1e-5f);
}

template<bool PRE>
__global__ __launch_bounds__(1024, 4) void rwkv_mfma(
    const float* __restrict__ X,
    const float* __restrict__ G0, const float* __restrict__ B0,
    const float* __restrict__ G1, const float* __restrict__ B1,
    const float* __restrict__ G2, const float* __restrict__ B2,
    const float* __restrict__ WoutF, const float* __restrict__ WwhtF,
    const float* __restrict__ WkeyF, const float* __restrict__ WrecF,
    const float* __restrict__ WvalF,
    const ushort* __restrict__ Wb,
    float* __restrict__ Y)
{
    __shared__ __align__(16) ushort actS[NW * TPW * LDA];   // 67584 B wave-local
    __shared__ __align__(16) ushort WldsA[128 * LDW];       // 34816 B: OUT,KEY*,REC
    __shared__ __align__(16) ushort WldsB[128 * LDW];       // 34816 B: WHT,VAL*
    // total 137216 B -> 1 block/CU; 16 waves/CU = 4 waves/SIMD

    const int tid = threadIdx.x;
    const int w = tid >> 6, l = tid & 63;
    const int q = l >> 4, c = l & 15;
    ushort* act = actS + w * (TPW * LDA);   // a1 / att / y2 / wht / k-chunk / prod

    const int s256 = blockIdx.x * 256;         // 256 tokens per block (16 waves x 16)
    const int bb  = s256 >> 14;
    const int s0  = s256 & (HW - 1);           // 16384%256==0: blocks never cross batch
    const long gbase = (long)(bb * CDIM) * HW + s0 + 16 * w + c;

    // ==== P0: stage OUT -> A (overlaps X loads + LN0/LN1) ====
    stageW<PRE>(WldsA, Wb + OFF_OUT, WoutF, 128, 0, 0, tid);

    float t[32];                               // fp32 residual (numerically required)
#pragma unroll
    for (int i = 0; i < 32; ++i) t[i] = X[gbase + (long)(32 * q + i) * HW];

    float mu, rs;
    ln_stats(t, mu, rs);                       // LN0
#pragma unroll
    for (int i = 0; i < 32; ++i) {
        int ch = 32 * q + i;
        t[i] = (t[i] - mu) * rs * G0[ch] + B0[ch];
    }
    ln_stats(t, mu, rs);                       // LN1 + silu -> act (a1)
#pragma unroll
    for (int j = 0; j < 16; ++j) {
        int ch = 32 * q + 2 * j;
        float y0 = (t[2*j]   - mu) * rs * G1[ch]   + B1[ch];
        float y1 = (t[2*j+1] - mu) * rs * G1[ch+1] + B1[ch+1];
        y0 *= sigm(y0); y1 *= sigm(y1);
        *(uint*)&act[c * LDA + ch] = pk2(y0, y1);
    }
    __syncthreads();                           // OUT staged

    // ==== P1: att = a1 @ W_out^T (A); stage WHT -> B; t1 = t + att ====
    stageW<PRE>(WldsB, Wb + OFF_WHT, WwhtF, 128, 0, 0, tid);
    {
        f32x4 acc[8];
        zero8(acc);
        gemm16(act, WldsA, q, c, acc);
        // D-store att -> act (overwrites a1; gemm reads precede in-wave)
#pragma unroll
        for (int nt = 0; nt < 8; ++nt)
#pragma unroll
            for (int r = 0; r < 4; ++r)
                act[(q * 4 + r) * LDA + nt * 16 + c] = f2bf(acc[nt][r]);
    }
    // in-wave cross-lane write->read (R8/R14/R15/R17-proven pattern class)
#pragma unroll
    for (int i = 0; i < 32; ++i)
        t[i] += bf2f(act[c * LDA + 32 * q + i]);    // t1 = t + att
    __syncthreads();                           // WHT staged, A free

    // ==== P2: y2 = LN2(t1) -> act; wht = y2 @ W_whiten^T (B) -> act;
    //          wa[] capture; stage KEY0 -> A ====
    stageW<PRE>(WldsA, Wb + OFF_KEY, WkeyF, 128, 0, 0, tid);
    ln_stats(t, mu, rs);                       // LN2
#pragma unroll
    for (int j = 0; j < 16; ++j) {
        int ch = 32 * q + 2 * j;
        float y0 = (t[2*j]   - mu) * rs * G2[ch]   + B2[ch];
        float y1 = (t[2*j+1] - mu) * rs * G2[ch+1] + B2[ch+1];
        *(uint*)&act[c * LDA + ch] = pk2(y0, y1);
    }
    {
        f32x4 acc[8];
        zero8(acc);
        gemm16(act, WldsB, q, c, acc);         // y2 writes precede reads in-wave
#pragma unroll
        for (int nt = 0; nt < 8; ++nt)         // D-store wht -> act
#pragma unroll
            for (int r = 0; r < 4; ++r)
                act[(q * 4 + r) * LDA + nt * 16 + c] = f2bf(acc[nt][r]);
    }
    // capture A-frags (same bf16 bits KEY/REC gemms would re-read); in-wave
    // cross-lane write->read, proven in R14/R15/R17.
    short8 wa[4];
#pragma unroll
    for (int kk = 0; kk < 4; ++kk)
        wa[kk] = ldA8(act + c * LDA + kk * 32 + q * 8);
    __syncthreads();                           // KEY0 staged, B free

    // ==== chunks: KEY_c on A (stage VAL_c -> B); VAL_c on B (stage next -> A) ====
    f32x4 akv[8];
    zero8(akv);
    for (int chunk = 0; chunk < 4; ++chunk) {
        // KEY phase: k = relu(wa @ W_key_c^T)^2 -> act, two half-N passes
        stageW<PRE>(WldsB, Wb + OFF_VAL, WvalF, 512, 0, chunk * 128, tid);
#pragma unroll
        for (int h = 0; h < 2; ++h) {
            f32x4 a4[4];
            zero4(a4);
            gemm8r(wa, WldsA, h * 4, q, c, a4);
#pragma unroll
            for (int g = 0; g < 4; ++g)
#pragma unroll
                for (int r = 0; r < 4; ++r) {
                    float v = fmaxf(a4[g][r], 0.f);
                    act[(q * 4 + r) * LDA + (h * 4 + g) * 16 + c] = f2bf(v * v);
                }
        }
        __syncthreads();                       // VAL_c staged, A free

        // VAL phase: akv += k @ W_value_c^T (k read from act, same wave wrote it)
        if (chunk < 3)
            stageW<PRE>(WldsA, Wb + OFF_KEY, WkeyF, 128, (chunk + 1) * 128, 0, tid);
        else
            stageW<PRE>(WldsA, Wb + OFF_REC, WrecF, 128, 0, 0, tid);
        gemm16(act, WldsB, q, c, akv);
        __syncthreads();                       // next tile staged, B free
    }

    // ==== P11: r = sigmoid(wa @ W_recep^T) (A); prod = r*kv -> act,
    //           two half-N passes ====
#pragma unroll
    for (int h = 0; h < 2; ++h) {
        f32x4 a4[4];
        zero4(a4);
        gemm8r(wa, WldsA, h * 4, q, c, a4);
#pragma unroll
        for (int g = 0; g < 4; ++g)
#pragma unroll
            for (int r = 0; r < 4; ++r)
                act[(q * 4 + r) * LDA + (h * 4 + g) * 16 + c] =
                    f2bf(sigm(a4[g][r]) * akv[h * 4 + g][r]);
    }
    // no barrier: act is wave-local; in-wave DS ordering covers the reads below.

    // ==== out = 2 * (t1 + r*kv) ====
#pragma unroll
    for (int i = 0; i < 32; ++i) {
        float t2 = t[i] + bf2f(act[c * LDA + 32 * q + i]);
        Y[gbase + (long)(32 * q + i) * HW] = 2.f * t2;
    }
}

extern "C" void kernel_launch(void* const* d_in, const int* in_sizes, int n_in,
                              void* d_out, int out_size, void* d_ws, size_t ws_size,
                              hipStream_t stream) {
    (void)in_sizes; (void)n_in; (void)out_size;
    const float* X  = (const float*)d_in[0];
    const float* G0 = (const float*)d_in[1];  const float* B0 = (const float*)d_in[2];
    const float* G1 = (const float*)d_in[3];  const float* B1 = (const float*)d_in[4];
    const float* G2 = (const float*)d_in[5];  const float* B2 = (const float*)d_in[6];
    const float* Wout = (const float*)d_in[7];
    const float* Wwht = (const float*)d_in[8];
    const float* Wkey = (const float*)d_in[9];
    const float* Wrec = (const float*)d_in[10];
    const float* Wval = (const float*)d_in[11];
    float* Y = (float*)d_out;

    const bool pre = ws_size >= (size_t)WS_ELEMS * 2;
    if (pre) {
        ushort* ws = (ushort*)d_ws;
        cvt_all<<<704, 256, 0, stream>>>(Wout, Wwht, Wkey, Wrec, Wval, ws);
        rwkv_mfma<true><<<256, 1024, 0, stream>>>(
            X, G0, B0, G1, B1, G2, B2,
            Wout, Wwht, Wkey, Wrec, Wval, ws, Y);
    } else {
        rwkv_mfma<false><<<256, 1024, 0, stream>>>(
            X, G0, B0, G1, B1, G2, B2,
            Wout, Wwht, Wkey, Wrec, Wval, nullptr, Y);
    }
}